// Round 5
// baseline (1135.140 us; speedup 1.0000x reference)
//
#include <hip/hip_runtime.h>
#include <cstddef>
#include <cstdint>

#define B_    128
#define NV_   100
#define NQ_   14
#define NA_   10
#define HDIM  512
#define RANK_ 32
#define HD_   16
#define G_    2

typedef __bf16 bf16x8 __attribute__((ext_vector_type(8)));
typedef float  f32x4  __attribute__((ext_vector_type(4)));
union Frag { uint4 u; bf16x8 v; };

__device__ __forceinline__ unsigned int f2bf(float f) {
  unsigned int u = __float_as_uint(f);
  u = (u + 0x7FFFu + ((u >> 16) & 1u)) >> 16;
  return u & 0xFFFFu;
}

__device__ __forceinline__ void gload_lds16(const unsigned short* gp,
                                            unsigned short* dp) {
  __builtin_amdgcn_global_load_lds(
      (const __attribute__((address_space(1))) void*)gp,
      (__attribute__((address_space(3))) void*)dp, 16, 0, 0);
}

// ---------------------------------------------------------------------------
// fp32 -> bf16 for q, a, and the six weight matrices (NOT v — converted inline
// in l1_gemm). dst is contiguous in this exact order.
__global__ __launch_bounds__(256) void cvt_kernel(
    const float* __restrict__ s0, const float* __restrict__ s1,
    const float* __restrict__ s2, const float* __restrict__ s3,
    const float* __restrict__ s4, const float* __restrict__ s5,
    const float* __restrict__ s6, const float* __restrict__ s7,
    unsigned short* __restrict__ dst)
{
  const int pref[8] = {896, 1536, 2048, 2304, 2560, 2688, 2816, 2944};
  const float* srcs[8] = {s0, s1, s2, s3, s4, s5, s6, s7};
  const int blk = blockIdx.x;
  int seg = 0;
  #pragma unroll
  for (int i = 0; i < 7; ++i) if (blk >= pref[i]) seg = i + 1;
  const int base_chunk = seg ? pref[seg - 1] : 0;
  const size_t loc = (size_t)(blk - base_chunk) * 2048 + threadIdx.x * 8;
  const float* s = srcs[seg] + loc;
  float4 f0 = *(const float4*)s;
  float4 f1 = *(const float4*)(s + 4);
  ushort4 o0, o1;
  o0.x = f2bf(f0.x); o0.y = f2bf(f0.y); o0.z = f2bf(f0.z); o0.w = f2bf(f0.w);
  o1.x = f2bf(f1.x); o1.y = f2bf(f1.y); o1.z = f2bf(f1.z); o1.w = f2bf(f1.w);
  unsigned short* d = dst + (size_t)blk * 2048 + threadIdx.x * 8;
  *(ushort4*)d = o0;
  *(ushort4*)(d + 4) = o1;
}

// ---------------------------------------------------------------------------
// Stage a 128x64 bf16 tile from global (row stride K elems) into LDS via
// global_load_lds (linear dest), 512 threads: 1024 16B-slots, 2 per thread.
// LDS layout: byte = row*128 + phys*16, phys = dataslot ^ (row&7)
// (XOR swizzle, conflict-free ds_read_b128 — verified SQ_LDS_BANK_CONFLICT=0).
// Swizzle applied on the per-lane GLOBAL source (m173 pattern).
__device__ __forceinline__ void stage_swz8(const unsigned short* __restrict__ src,
                                           int K, unsigned short* dst, int t)
{
  const int wb = t & 448;   // wave_id * 64 (wave-uniform)
  const int l = t & 63;
  #pragma unroll
  for (int i = 0; i < 2; ++i) {
    const int sb = i * 512 + wb;           // uniform 16B-slot base
    const int li = sb + l;                 // 0..1023
    const int row = li >> 3;
    const int p = li & 7;
    const int s = p ^ (row & 7);           // data slot held at phys slot p
    gload_lds16(src + (size_t)row * K + s * 8, dst + sb * 8);
  }
}

// Convert 16 fp32 (4 float4) to bf16 and write swizzled into a 128x64 A tile.
// Thread owns row ar, data slots {2*kq, 2*kq+1}.
__device__ __forceinline__ void cvt_write(const float4 f0, const float4 f1,
                                          const float4 f2, const float4 f3,
                                          unsigned short* Abuf, int ar, int kq)
{
  unsigned short* base = Abuf + ar * 64;
  uint4 p0, p1;
  p0.x = f2bf(f0.x) | (f2bf(f0.y) << 16);
  p0.y = f2bf(f0.z) | (f2bf(f0.w) << 16);
  p0.z = f2bf(f1.x) | (f2bf(f1.y) << 16);
  p0.w = f2bf(f1.z) | (f2bf(f1.w) << 16);
  p1.x = f2bf(f2.x) | (f2bf(f2.y) << 16);
  p1.y = f2bf(f2.z) | (f2bf(f2.w) << 16);
  p1.z = f2bf(f3.x) | (f2bf(f3.y) << 16);
  p1.w = f2bf(f3.z) | (f2bf(f3.w) << 16);
  *(uint4*)&base[((kq * 2 + 0) ^ (ar & 7)) * 8] = p0;
  *(uint4*)&base[((kq * 2 + 1) ^ (ar & 7)) * 8] = p1;
}

// One k-half compute step: wave covers a 64x64 output quadrant for ONE 32-wide
// k-slice (kh) of the BK=64 tile: 8 ds_read_b128 + 16 MFMA (0.5 KB LDS / MFMA).
__device__ __forceinline__ void compute_h(const unsigned short* Ad,
                                          const unsigned short* Bd,
                                          int wm, int wn, int kh, int l,
                                          f32x4 acc[4][4])
{
  Frag fa[4], fb[4];
  const int slot = kh * 4 + (l >> 4);
  #pragma unroll
  for (int i = 0; i < 4; ++i) {
    const int r = wm + 16 * i + (l & 15);
    fa[i].u = *(const uint4*)&Ad[r * 64 + ((slot ^ (r & 7)) * 8)];
  }
  #pragma unroll
  for (int j = 0; j < 4; ++j) {
    const int r = wn + 16 * j + (l & 15);
    fb[j].u = *(const uint4*)&Bd[r * 64 + ((slot ^ (r & 7)) * 8)];
  }
  #pragma unroll
  for (int i = 0; i < 4; ++i)
    #pragma unroll
    for (int j = 0; j < 4; ++j)
      acc[i][j] = __builtin_amdgcn_mfma_f32_16x16x32_bf16(fa[i].v, fb[j].v, acc[i][j], 0, 0, 0);
}

// ---------------------------------------------------------------------------
// Grouped layer-1 GEMM. 128x128 tiles, BK=64, 512 threads. 8 waves = 4 output
// quadrants (64x64) x 2 k-halves: each wave does 8 ds_read_b128 + 16 MFMA per
// step (33% less LDS-read traffic than the 64x32 wave tile). K-half partials
// are combined through an LDS reduce at the epilogue. Plain __syncthreads
// (R2-proven). v: 400 blocks XCD-chunked. grid = 496.
__global__ __launch_bounds__(512, 4) void l1_gemm(
    const float* __restrict__ v,
    const unsigned short* __restrict__ qb, const unsigned short* __restrict__ ab,
    const unsigned short* __restrict__ Wvb, const unsigned short* __restrict__ Wqb,
    const unsigned short* __restrict__ Wab,
    const float* __restrict__ bv, const float* __restrict__ bq,
    const float* __restrict__ ba,
    unsigned short* __restrict__ vtb, unsigned short* __restrict__ qtb,
    unsigned short* __restrict__ atb)
{
  __shared__ __align__(16) unsigned short SH[32768];   // 64 KB
  unsigned short (*As)[8192] = (unsigned short (*)[8192])(SH);          // 2 x 16 KB
  unsigned short (*Bs)[8192] = (unsigned short (*)[8192])(SH + 16384);  // 2 x 16 KB
  const int bx = blockIdx.x;
  int grp, gx, gy, K;
  const unsigned short *A16 = qb, *W;
  const float* bias;
  unsigned short* C;
  if (bx < 400) {
    grp = 0; const int xcd = bx & 7, j = bx >> 3; const int m = xcd * 50 + j;
    gy = m >> 2; gx = m & 3; W = Wvb; bias = bv; C = vtb; K = 2048;
  } else if (bx < 456) {
    grp = 1; const int lo = bx - 400; gy = lo >> 2; gx = lo & 3;
    A16 = qb; W = Wqb; bias = bq; C = qtb; K = 1024;
  } else {
    grp = 2; const int lo = bx - 456; gy = lo >> 2; gx = lo & 3;
    A16 = ab; W = Wab; bias = ba; C = atb; K = 1024;
  }
  const int nsteps = K >> 6;
  const bool isv = (grp == 0);
  const int bm = gy * 128, bn = gx * 128;
  const int t = threadIdx.x;
  const int w = t >> 6, l = t & 63;
  const int qd = w & 3, kh = w >> 2;
  const int wm = (qd >> 1) * 64, wn = (qd & 1) * 64;
  const int ar = t >> 2, kq = t & 3;

  f32x4 acc[4][4];
  #pragma unroll
  for (int i = 0; i < 4; ++i)
    #pragma unroll
    for (int j = 0; j < 4; ++j) acc[i][j] = f32x4{0.f, 0.f, 0.f, 0.f};

  // v-group A staging: thread owns 16 floats (quarter row) per step
  const float* vrow = isv ? v + (size_t)(bm + ar) * 2048 + kq * 16
                          : (const float*)nullptr;
  float4 R0, R1, R2, R3, R4, R5, R6, R7;

  // ---- prologue (R2-proven shape)
  stage_swz8(W + (size_t)bn * K, K, Bs[0], t);
  if (isv) {
    { const float4* p = (const float4*)vrow;
      R0 = p[0]; R1 = p[1]; R2 = p[2]; R3 = p[3]; }
    { const float4* p = (const float4*)(vrow + 64);
      R4 = p[0]; R5 = p[1]; R6 = p[2]; R7 = p[3]; }
    cvt_write(R0, R1, R2, R3, As[0], ar, kq);
  } else {
    stage_swz8(A16 + (size_t)bm * K, K, As[0], t);
  }
  __syncthreads();

  for (int step = 0; step < nsteps; ++step) {
    const int db = step & 1;
    const bool hn = (step + 1) < nsteps;
    if (hn) stage_swz8(W + (size_t)bn * K + (step + 1) * 64, K, Bs[db ^ 1], t);
    if (isv) {
      if (step + 2 < nsteps) {
        const float* p = vrow + (step + 2) * 64;
        if (db == 0) {
          const float4* q4p = (const float4*)p;
          R0 = q4p[0]; R1 = q4p[1]; R2 = q4p[2]; R3 = q4p[3];
        } else {
          const float4* q4p = (const float4*)p;
          R4 = q4p[0]; R5 = q4p[1]; R6 = q4p[2]; R7 = q4p[3];
        }
      }
      if (hn) {
        if (db == 0) cvt_write(R4, R5, R6, R7, As[1], ar, kq);
        else         cvt_write(R0, R1, R2, R3, As[0], ar, kq);
      }
    } else if (hn) {
      stage_swz8(A16 + (size_t)bm * K + (step + 1) * 64, K, As[db ^ 1], t);
    }
    compute_h(As[db], Bs[db], wm, wn, kh, l, acc);
    __syncthreads();
  }

  // ---- k-half reduce through LDS (SH reused as f32 scratch, 16384 floats).
  // Region A (floats 0..8191):    written by kh=1 (its i=0,1 partials)
  // Region B (floats 8192..16383): written by kh=0 (its i=2,3 partials)
  float* red = (float*)SH;
  const int q4 = (l >> 4) * 4, cl = l & 15;
  {
    float* dst = red + (kh ? 0 : 8192) + qd * 2048;
    const int ig = kh ? 0 : 2;   // rows given away to the partner
    #pragma unroll
    for (int ii = 0; ii < 2; ++ii)
      #pragma unroll
      for (int j = 0; j < 4; ++j)
        #pragma unroll
        for (int r = 0; r < 4; ++r)
          dst[(ii * 16 + q4 + r) * 64 + 16 * j + cl] = acc[ig + ii][j][r];
  }
  __syncthreads();
  const int ik = kh ? 2 : 0;     // rows this wave keeps and stores
  {
    const float* src = red + (kh ? 8192 : 0) + qd * 2048;
    #pragma unroll
    for (int ii = 0; ii < 2; ++ii)
      #pragma unroll
      for (int j = 0; j < 4; ++j)
        #pragma unroll
        for (int r = 0; r < 4; ++r)
          acc[ik + ii][j][r] += src[(ii * 16 + q4 + r) * 64 + 16 * j + cl];
  }

  #pragma unroll
  for (int ii = 0; ii < 2; ++ii)
    #pragma unroll
    for (int j = 0; j < 4; ++j) {
      const int col = bn + wn + 16 * j + cl;
      const float bs = bias[col];
      #pragma unroll
      for (int r = 0; r < 4; ++r) {
        const int row = bm + wm + 16 * (ik + ii) + q4 + r;
        float o = fmaxf(acc[ik + ii][j][r] + bs, 0.f);
        C[(size_t)row * 512 + col] = (unsigned short)f2bf(o);
      }
    }
}

// ---------------------------------------------------------------------------
// Grouped layer-2 GEMM, same k-split template. A and B both gload_lds staged
// (all-bf16). K=512 (8 steps). v out bf16, q/a out fp32. grid = 496.
__global__ __launch_bounds__(512, 4) void l2_gemm(
    const unsigned short* __restrict__ vtb, const unsigned short* __restrict__ qtb,
    const unsigned short* __restrict__ atb,
    const unsigned short* __restrict__ Wvrb, const unsigned short* __restrict__ Wqrb,
    const unsigned short* __restrict__ Warb,
    const float* __restrict__ bvr, const float* __restrict__ bqr,
    const float* __restrict__ bar_,
    unsigned short* __restrict__ vrb, float* __restrict__ q_r, float* __restrict__ a_r)
{
  __shared__ __align__(16) unsigned short SH[32768];
  unsigned short (*As)[8192] = (unsigned short (*)[8192])(SH);
  unsigned short (*Bs)[8192] = (unsigned short (*)[8192])(SH + 16384);
  const int bx = blockIdx.x;
  int grp, gx, gy;
  const unsigned short *A16, *W;
  const float* bias;
  if (bx < 400) {
    grp = 0; const int xcd = bx & 7, j = bx >> 3; const int m = xcd * 50 + j;
    gy = m >> 2; gx = m & 3; A16 = vtb; W = Wvrb; bias = bvr;
  } else if (bx < 456) {
    grp = 1; const int lo = bx - 400; gy = lo >> 2; gx = lo & 3;
    A16 = qtb; W = Wqrb; bias = bqr;
  } else {
    grp = 2; const int lo = bx - 456; gy = lo >> 2; gx = lo & 3;
    A16 = atb; W = Warb; bias = bar_;
  }
  const int nsteps = 8;
  const int bm = gy * 128, bn = gx * 128;
  const int t = threadIdx.x;
  const int w = t >> 6, l = t & 63;
  const int qd = w & 3, kh = w >> 2;
  const int wm = (qd >> 1) * 64, wn = (qd & 1) * 64;

  f32x4 acc[4][4];
  #pragma unroll
  for (int i = 0; i < 4; ++i)
    #pragma unroll
    for (int j = 0; j < 4; ++j) acc[i][j] = f32x4{0.f, 0.f, 0.f, 0.f};

  stage_swz8(W + (size_t)bn * 512, 512, Bs[0], t);
  stage_swz8(A16 + (size_t)bm * 512, 512, As[0], t);
  __syncthreads();

  for (int step = 0; step < nsteps; ++step) {
    const int db = step & 1;
    const bool hn = (step + 1) < nsteps;
    const int k0n = (step + 1) << 6;
    if (hn) {
      stage_swz8(W + (size_t)bn * 512 + k0n, 512, Bs[db ^ 1], t);
      stage_swz8(A16 + (size_t)bm * 512 + k0n, 512, As[db ^ 1], t);
    }
    compute_h(As[db], Bs[db], wm, wn, kh, l, acc);
    __syncthreads();
  }

  float* red = (float*)SH;
  const int q4 = (l >> 4) * 4, cl = l & 15;
  {
    float* dst = red + (kh ? 0 : 8192) + qd * 2048;
    const int ig = kh ? 0 : 2;
    #pragma unroll
    for (int ii = 0; ii < 2; ++ii)
      #pragma unroll
      for (int j = 0; j < 4; ++j)
        #pragma unroll
        for (int r = 0; r < 4; ++r)
          dst[(ii * 16 + q4 + r) * 64 + 16 * j + cl] = acc[ig + ii][j][r];
  }
  __syncthreads();
  const int ik = kh ? 2 : 0;
  {
    const float* src = red + (kh ? 8192 : 0) + qd * 2048;
    #pragma unroll
    for (int ii = 0; ii < 2; ++ii)
      #pragma unroll
      for (int j = 0; j < 4; ++j)
        #pragma unroll
        for (int r = 0; r < 4; ++r)
          acc[ik + ii][j][r] += src[(ii * 16 + q4 + r) * 64 + 16 * j + cl];
  }

  #pragma unroll
  for (int ii = 0; ii < 2; ++ii)
    #pragma unroll
    for (int j = 0; j < 4; ++j) {
      const int col = bn + wn + 16 * j + cl;
      const float bs = bias[col];
      #pragma unroll
      for (int r = 0; r < 4; ++r) {
        const int row = bm + wm + 16 * (ik + ii) + q4 + r;
        float o = fmaxf(acc[ik + ii][j][r] + bs, 0.f);
        if (grp == 0)      vrb[(size_t)row * 512 + col] = (unsigned short)f2bf(o);
        else if (grp == 1) q_r[(size_t)row * 512 + col] = o;
        else               a_r[(size_t)row * 512 + col] = o;
      }
    }
}

// ---------------------------------------------------------------------------
__global__ void tsum_kernel(const float* __restrict__ T, float* __restrict__ Tsum)
{
  const int idx = blockIdx.x * 256 + threadIdx.x;
  float s = 0.f;
  #pragma unroll
  for (int r = 0; r < RANK_; ++r) s += T[r * 8192 + idx];
  Tsum[idx] = s;
}

// ---------------------------------------------------------------------------
// Per (b,n): U = Tsum x q_ ; WmatT[b, col, n*16+i] = bf16(U x a_)
// WmatT padded to 320 rows (cols 280..319 unwritten).
__global__ __launch_bounds__(256) void build_w_kernel(
    const float* __restrict__ q_, const float* __restrict__ a_,
    const float* __restrict__ Tsum, unsigned short* __restrict__ WmatT)
{
  const int n = blockIdx.x, b = blockIdx.y, t = threadIdx.x;
  __shared__ float Ts[8192];
  __shared__ float U[14 * 544];

  #pragma unroll
  for (int s = 0; s < 8; ++s)
    ((float4*)Ts)[s * 256 + t] = ((const float4*)Tsum)[s * 256 + t];
  __syncthreads();

  {
    const int i = t >> 4, k = t & 15;
    float acc0[NQ_], acc1[NQ_];
    #pragma unroll
    for (int q = 0; q < NQ_; ++q) { acc0[q] = 0.f; acc1[q] = 0.f; }
    const float* qbase = q_ + (size_t)b * NQ_ * HDIM + n * 16;
    #pragma unroll
    for (int j = 0; j < 16; ++j) {
      float2 ts = *(const float2*)&Ts[i * 512 + j * 32 + k * 2];
      #pragma unroll
      for (int q = 0; q < NQ_; ++q) {
        float qv = qbase[q * HDIM + j];
        acc0[q] += ts.x * qv;
        acc1[q] += ts.y * qv;
      }
    }
    #pragma unroll
    for (int q = 0; q < NQ_; ++q) {
      float2 uu; uu.x = acc0[q]; uu.y = acc1[q];
      *(float2*)&U[q * 544 + i * 34 + k * 2] = uu;
    }
  }
  __syncthreads();

  if ((t >> 4) < NQ_) {
    const int q = t >> 4, i = t & 15;
    float acc0[NA_], acc1[NA_];
    #pragma unroll
    for (int a = 0; a < NA_; ++a) { acc0[a] = 0.f; acc1[a] = 0.f; }
    const float* abase = a_ + (size_t)b * NA_ * HDIM + n * 16;
    #pragma unroll
    for (int k = 0; k < 16; ++k) {
      float2 uu = *(const float2*)&U[q * 544 + i * 34 + k * 2];
      #pragma unroll
      for (int a = 0; a < NA_; ++a) {
        float av = abase[a * HDIM + k];
        acc0[a] += uu.x * av;
        acc1[a] += uu.y * av;
      }
    }
    unsigned short* wb = WmatT + (size_t)b * 320 * 512 + (n * 16 + i);
    #pragma unroll
    for (int a = 0; a < NA_; ++a) {
      wb[(size_t)((q * 10 + a) * 2 + 0) * 512] = (unsigned short)f2bf(acc0[a]);
      wb[(size_t)((q * 10 + a) * 2 + 1) * 512] = (unsigned short)f2bf(acc1[a]);
    }
  }
}

// ---------------------------------------------------------------------------
// Stage one BK=32 K-slice of final_mfma's A (64x32) and B (160x32) tiles.
__device__ __forceinline__ void final_stage(
    const unsigned short* __restrict__ Vrb, const unsigned short* __restrict__ Wb,
    int b, int mh, int n0, int k0, int t,
    unsigned short* Asb, unsigned short* Bsb)
{
  const int w = t >> 6, l = t & 63;
  {
    int grow = b * NV_ + mh * 64 + w * 16 + (l >> 2);
    if (grow > B_ * NV_ - 1) grow = B_ * NV_ - 1;   // clamp pad rows
    gload_lds16(Vrb + (size_t)grow * HDIM + k0 + (l & 3) * 8, &Asb[w * 512]);
  }
  #pragma unroll
  for (int c = 0; c < 3; ++c) {
    const int base = c * 256 + w * 64;   // 640 chunks of 16B
    if (base < 640) {
      const int li = base + l;
      const int nrow = li >> 2, ko2 = (li & 3) * 8;
      gload_lds16(Wb + (size_t)(n0 + nrow) * 512 + k0 + ko2, &Bsb[base * 8]);
    }
  }
}

// ---------------------------------------------------------------------------
// out[b,100,280] = v_[b,100,512] @ WmatT[b,320,512]^T
// grid (4, 128): blockIdx.x = mh*2 + nh; 64-row m-tile, 160-col n-tile.
// BK=32, 16 steps, 1-step-prefetch double buffer.
__global__ __launch_bounds__(256) void final_mfma(
    const unsigned short* __restrict__ Vrb, const unsigned short* __restrict__ WmatT,
    float* __restrict__ out)
{
  __shared__ __align__(16) unsigned short As[2][2048];   // [64][32]
  __shared__ __align__(16) unsigned short Bs[2][5120];   // [160][32]
  const int b  = blockIdx.y;
  const int mh = blockIdx.x >> 1;
  const int n0 = (blockIdx.x & 1) * 160;
  const int t = threadIdx.x;
  const int w = t >> 6, l = t & 63;
  const int wm = (w >> 1) * 32;   // 0,32 within 64-row tile
  const int wn = (w & 1) * 80;    // 0,80 within 160-col tile

  f32x4 acc[2][5];
  #pragma unroll
  for (int mi = 0; mi < 2; ++mi)
    #pragma unroll
    for (int nj = 0; nj < 5; ++nj) acc[mi][nj] = f32x4{0.f, 0.f, 0.f, 0.f};

  const unsigned short* Wb = WmatT + (size_t)b * 320 * 512;

  final_stage(Vrb, Wb, b, mh, n0, 0, t, As[0], Bs[0]);
  __syncthreads();

  for (int step = 0; step < 16; ++step) {
    const int db = step & 1;
    if (step + 1 < 16)
      final_stage(Vrb, Wb, b, mh, n0, (step + 1) * 32, t, As[db ^ 1], Bs[db ^ 1]);

    Frag fa[2], fb[5];
    #pragma unroll
    for (int mi = 0; mi < 2; ++mi)
      fa[mi].u = *(const uint4*)&As[db][(wm + mi * 16 + (l & 15)) * 32 + (l >> 4) * 8];
    #pragma unroll
    for (int nj = 0; nj < 5; ++nj)
      fb[nj].u = *(const uint4*)&Bs[db][(wn + nj * 16 + (l & 15)) * 32 + (l >> 4) * 8];
    #pragma unroll
    for (int mi = 0; mi < 2; ++mi)
      #pragma unroll
      for (int nj = 0; nj < 5; ++nj)
        acc[mi][nj] = __builtin_amdgcn_mfma_f32_16x16x32_bf16(fa[mi].v, fb[nj].v, acc[mi][nj], 0, 0, 0);
    __syncthreads();
  }

  #pragma unroll
  for (int mi = 0; mi < 2; ++mi)
    #pragma unroll
    for (int nj = 0; nj < 5; ++nj) {
      const int col = n0 + wn + nj * 16 + (l & 15);
      if (col < 280) {
        #pragma unroll
        for (int r = 0; r < 4; ++r) {
          const int row = mh * 64 + wm + mi * 16 + (l >> 4) * 4 + r;
          if (row < NV_)
            out[((size_t)b * NV_ + row) * 280 + col] = acc[mi][nj][r];
        }
      }
    }
}

// ---------------------------------------------------------------------------
extern "C" void kernel_launch(void* const* d_in, const int* in_sizes, int n_in,
                              void* d_out, int out_size, void* d_ws, size_t ws_size,
                              hipStream_t stream)
{
  const float* v   = (const float*)d_in[0];
  const float* q   = (const float*)d_in[1];
  const float* a   = (const float*)d_in[2];
  const float* Wv  = (const float*)d_in[3];
  const float* bv  = (const float*)d_in[4];
  const float* Wq  = (const float*)d_in[5];
  const float* bq  = (const float*)d_in[6];
  const float* Wa  = (const float*)d_in[7];
  const float* ba  = (const float*)d_in[8];
  const float* Wvr = (const float*)d_in[9];
  const float* bvr = (const float*)d_in[10];
  const float* Wqr = (const float*)d_in[11];
  const float* bqr = (const float*)d_in[12];
  const float* War = (const float*)d_in[13];
  const float* bar = (const float*)d_in[14];
  const float* T   = (const float*)d_in[15];

  unsigned short* wsu = (unsigned short*)d_ws;
  float* wsf = (float*)d_ws;

  // region A (ushort): WmatT [0 .. 20,971,520) — early overlay: bf16 q/a/weights
  unsigned short* WmatT = wsu;
  unsigned short* qb    = wsu;              //  1,835,008 (dead after l1)
  unsigned short* ab    = wsu + 1835008;    //  1,310,720 (dead after l1)
  unsigned short* Wvb   = wsu + 3145728;    //  1,048,576 (dead after l1)
  unsigned short* Wqb   = wsu + 4194304;    //    524,288
  unsigned short* Wab   = wsu + 4718592;    //    524,288
  unsigned short* Wvrb  = wsu + 5242880;    //    262,144 (dead after l2)
  unsigned short* Wqrb  = wsu + 5505024;    //    262,144
  unsigned short* Warb  = wsu + 5767168;    //    262,144  end 6,029,312 < 20.97M ok
  // persistent bf16 intermediates
  unsigned short* vtb   = wsu + 20971520;   //  6,553,600
  unsigned short* qtb   = wsu + 27525120;   //    917,504
  unsigned short* atb   = wsu + 28442624;   //    655,360
  unsigned short* vrb   = wsu + 29097984;   //  6,553,600  end 35,651,584 ush
  // fp32 region
  float* q_r  = wsf + 17825792;             //    917,504 f
  float* a_r  = wsf + 18743296;             //    655,360 f
  float* Tsum = wsf + 19398656;             //      8,192 f   (end 77.6 MB)

  cvt_kernel<<<2944, 256, 0, stream>>>(q, a, Wv, Wq, Wa, Wvr, Wqr, War, wsu);

  l1_gemm<<<496, 512, 0, stream>>>(v, qb, ab, Wvb, Wqb, Wab, bv, bq, ba,
                                   vtb, qtb, atb);
  l2_gemm<<<496, 512, 0, stream>>>(vtb, qtb, atb, Wvrb, Wqrb, Warb,
                                   bvr, bqr, bar, vrb, q_r, a_r);

  tsum_kernel<<<32, 256, 0, stream>>>(T, Tsum);
  build_w_kernel<<<dim3(32, 128), 256, 0, stream>>>(q_r, a_r, Tsum, WmatT);
  final_mfma<<<dim3(4, 128), 256, 0, stream>>>(vrb, WmatT, (float*)d_out);
}

// Round 6
// 463.902 us; speedup vs baseline: 2.4469x; 2.4469x over previous
//
#include <hip/hip_runtime.h>
#include <cstddef>
#include <cstdint>

#define B_    128
#define NV_   100
#define NQ_   14
#define NA_   10
#define HDIM  512
#define RANK_ 32
#define HD_   16
#define G_    2

typedef __bf16 bf16x8 __attribute__((ext_vector_type(8)));
typedef float  f32x4  __attribute__((ext_vector_type(4)));
union Frag { uint4 u; bf16x8 v; };

__device__ __forceinline__ unsigned int f2bf(float f) {
  unsigned int u = __float_as_uint(f);
  u = (u + 0x7FFFu + ((u >> 16) & 1u)) >> 16;
  return u & 0xFFFFu;
}

__device__ __forceinline__ void gload_lds16(const unsigned short* gp,
                                            unsigned short* dp) {
  __builtin_amdgcn_global_load_lds(
      (const __attribute__((address_space(1))) void*)gp,
      (__attribute__((address_space(3))) void*)dp, 16, 0, 0);
}

// ---------------------------------------------------------------------------
// fp32 -> bf16 for q, a, and the six weight matrices (NOT v — converted inline
// in l1_gemm). dst is contiguous in this exact order.
__global__ __launch_bounds__(256) void cvt_kernel(
    const float* __restrict__ s0, const float* __restrict__ s1,
    const float* __restrict__ s2, const float* __restrict__ s3,
    const float* __restrict__ s4, const float* __restrict__ s5,
    const float* __restrict__ s6, const float* __restrict__ s7,
    unsigned short* __restrict__ dst)
{
  const int pref[8] = {896, 1536, 2048, 2304, 2560, 2688, 2816, 2944};
  const float* srcs[8] = {s0, s1, s2, s3, s4, s5, s6, s7};
  const int blk = blockIdx.x;
  int seg = 0;
  #pragma unroll
  for (int i = 0; i < 7; ++i) if (blk >= pref[i]) seg = i + 1;
  const int base_chunk = seg ? pref[seg - 1] : 0;
  const size_t loc = (size_t)(blk - base_chunk) * 2048 + threadIdx.x * 8;
  const float* s = srcs[seg] + loc;
  float4 f0 = *(const float4*)s;
  float4 f1 = *(const float4*)(s + 4);
  ushort4 o0, o1;
  o0.x = f2bf(f0.x); o0.y = f2bf(f0.y); o0.z = f2bf(f0.z); o0.w = f2bf(f0.w);
  o1.x = f2bf(f1.x); o1.y = f2bf(f1.y); o1.z = f2bf(f1.z); o1.w = f2bf(f1.w);
  unsigned short* d = dst + (size_t)blk * 2048 + threadIdx.x * 8;
  *(ushort4*)d = o0;
  *(ushort4*)(d + 4) = o1;
}

// ---------------------------------------------------------------------------
// Stage a 128x64 bf16 tile from global (row stride K elems) into LDS via
// global_load_lds (linear dest), 512 threads: 1024 16B-slots, 2 per thread.
// LDS layout: byte = row*128 + phys*16, phys = dataslot ^ (row&7)
// (XOR swizzle, conflict-free ds_read_b128 — verified SQ_LDS_BANK_CONFLICT=0).
// Swizzle applied on the per-lane GLOBAL source (m173 pattern).
__device__ __forceinline__ void stage_swz8(const unsigned short* __restrict__ src,
                                           int K, unsigned short* dst, int t)
{
  const int wb = t & 448;   // wave_id * 64 (wave-uniform)
  const int l = t & 63;
  #pragma unroll
  for (int i = 0; i < 2; ++i) {
    const int sb = i * 512 + wb;           // uniform 16B-slot base
    const int li = sb + l;                 // 0..1023
    const int row = li >> 3;
    const int p = li & 7;
    const int s = p ^ (row & 7);           // data slot held at phys slot p
    gload_lds16(src + (size_t)row * K + s * 8, dst + sb * 8);
  }
}

// Convert 16 fp32 (4 float4) to bf16 and write swizzled into a 128x64 A tile.
// Thread owns row ar, data slots {2*kq, 2*kq+1}.
__device__ __forceinline__ void cvt_write(const float4 f0, const float4 f1,
                                          const float4 f2, const float4 f3,
                                          unsigned short* Abuf, int ar, int kq)
{
  unsigned short* base = Abuf + ar * 64;
  uint4 p0, p1;
  p0.x = f2bf(f0.x) | (f2bf(f0.y) << 16);
  p0.y = f2bf(f0.z) | (f2bf(f0.w) << 16);
  p0.z = f2bf(f1.x) | (f2bf(f1.y) << 16);
  p0.w = f2bf(f1.z) | (f2bf(f1.w) << 16);
  p1.x = f2bf(f2.x) | (f2bf(f2.y) << 16);
  p1.y = f2bf(f2.z) | (f2bf(f2.w) << 16);
  p1.z = f2bf(f3.x) | (f2bf(f3.y) << 16);
  p1.w = f2bf(f3.z) | (f2bf(f3.w) << 16);
  *(uint4*)&base[((kq * 2 + 0) ^ (ar & 7)) * 8] = p0;
  *(uint4*)&base[((kq * 2 + 1) ^ (ar & 7)) * 8] = p1;
}

// One BK=64 compute step: 12 ds_read_b128 + 16 MFMA per wave (R2-proven).
__device__ __forceinline__ void compute64(const unsigned short* Ad,
                                          const unsigned short* Bd,
                                          int wm, int wn, int l,
                                          f32x4 acc[4][2])
{
  #pragma unroll
  for (int ks = 0; ks < 2; ++ks) {
    Frag fa[4], fb[2];
    #pragma unroll
    for (int i = 0; i < 4; ++i) {
      const int r = wm + 16 * i + (l & 15);
      fa[i].u = *(const uint4*)&Ad[r * 64 + (((ks * 4 + (l >> 4)) ^ (r & 7)) * 8)];
    }
    #pragma unroll
    for (int j = 0; j < 2; ++j) {
      const int r = wn + 16 * j + (l & 15);
      fb[j].u = *(const uint4*)&Bd[r * 64 + (((ks * 4 + (l >> 4)) ^ (r & 7)) * 8)];
    }
    #pragma unroll
    for (int i = 0; i < 4; ++i)
      #pragma unroll
      for (int j = 0; j < 2; ++j)
        acc[i][j] = __builtin_amdgcn_mfma_f32_16x16x32_bf16(fa[i].v, fb[j].v, acc[i][j], 0, 0, 0);
  }
}

// ---------------------------------------------------------------------------
// Grouped layer-1 GEMM. 128x128 tiles, BK=64, 512 threads, wave tile 64x32
// (R2-proven). LDS cut to 48 KB: A double-buffered, B SINGLE-buffered ->
// 3 blocks/CU (24 waves) so cross-block overlap (m114) hides the B-stage
// drain at the second barrier. Two __syncthreads per step:
//   bar1 (B+A[db^1] read-free) ; stage B[k] ; write A[k+1] ; bar2 ; compute.
// v: A reg-staged distance 2 (fp32 load after bar2, cvt_write next step).
// grid = 496 (400 v XCD-chunked, 56 q, 40 a).
__global__ __launch_bounds__(512, 6) void l1_gemm(
    const float* __restrict__ v,
    const unsigned short* __restrict__ qb, const unsigned short* __restrict__ ab,
    const unsigned short* __restrict__ Wvb, const unsigned short* __restrict__ Wqb,
    const unsigned short* __restrict__ Wab,
    const float* __restrict__ bv, const float* __restrict__ bq,
    const float* __restrict__ ba,
    unsigned short* __restrict__ vtb, unsigned short* __restrict__ qtb,
    unsigned short* __restrict__ atb)
{
  __shared__ __align__(16) unsigned short As[2][8192];   // 32 KB (A dbuf)
  __shared__ __align__(16) unsigned short Bs1[8192];     // 16 KB (B single)
  const int bx = blockIdx.x;
  int grp, gx, gy, K;
  const unsigned short *A16 = qb, *W;
  const float* bias;
  unsigned short* C;
  if (bx < 400) {
    grp = 0; const int xcd = bx & 7, j = bx >> 3; const int m = xcd * 50 + j;
    gy = m >> 2; gx = m & 3; W = Wvb; bias = bv; C = vtb; K = 2048;
  } else if (bx < 456) {
    grp = 1; const int lo = bx - 400; gy = lo >> 2; gx = lo & 3;
    A16 = qb; W = Wqb; bias = bq; C = qtb; K = 1024;
  } else {
    grp = 2; const int lo = bx - 456; gy = lo >> 2; gx = lo & 3;
    A16 = ab; W = Wab; bias = ba; C = atb; K = 1024;
  }
  const int nsteps = K >> 6;
  const bool isv = (grp == 0);
  const int bm = gy * 128, bn = gx * 128;
  const int t = threadIdx.x;
  const int w = t >> 6, l = t & 63;
  const int wm = (w >> 2) * 64, wn = (w & 3) * 32;
  const int ar = t >> 2, kq = t & 3;

  const float* vrow = isv ? v + (size_t)(bm + ar) * 2048 + kq * 16
                          : (const float*)nullptr;
  const unsigned short* Wrow = W + (size_t)bn * K;

  f32x4 acc[4][2];
  #pragma unroll
  for (int i = 0; i < 4; ++i)
    #pragma unroll
    for (int j = 0; j < 2; ++j) acc[i][j] = f32x4{0.f, 0.f, 0.f, 0.f};

  // Register halves: R0-R3 hold A[even k], R4-R7 hold A[odd k].
  float4 R0, R1, R2, R3, R4, R5, R6, R7;

  // ---- prologue: A[0],A[1] -> regs (v) or A[0] -> LDS (q/a); write A[0].
  if (isv) {
    { const float4* p = (const float4*)vrow;
      R0 = p[0]; R1 = p[1]; R2 = p[2]; R3 = p[3]; }
    { const float4* p = (const float4*)(vrow + 64);
      R4 = p[0]; R5 = p[1]; R6 = p[2]; R7 = p[3]; }
    cvt_write(R0, R1, R2, R3, As[0], ar, kq);
  } else {
    stage_swz8(A16 + (size_t)bm * K, K, As[0], t);
  }

  int db = 0;
  for (int step = 0; step < nsteps; ++step) {
    __syncthreads();                                   // bar1: buffers free
    stage_swz8(Wrow + step * 64, K, Bs1, t);           // B[k] (drained at bar2)
    if (isv && (step + 1) < nsteps) {
      if ((step + 1) & 1) cvt_write(R4, R5, R6, R7, As[db ^ 1], ar, kq);
      else                cvt_write(R0, R1, R2, R3, As[db ^ 1], ar, kq);
    }
    __syncthreads();                                   // bar2: B[k], A[k+1] ready
    if (isv) {
      if (step + 2 < nsteps) {                         // A[k+2] -> regs, in
        const float4* p = (const float4*)(vrow + (step + 2) * 64);   // flight
        if (step & 1) { R4 = p[0]; R5 = p[1]; R6 = p[2]; R7 = p[3]; }
        else          { R0 = p[0]; R1 = p[1]; R2 = p[2]; R3 = p[3]; }
      }
    } else if (step + 1 < nsteps) {                    // A[k+1] -> LDS, in
      stage_swz8(A16 + (size_t)bm * K + (step + 1) * 64, K, As[db ^ 1], t);
    }
    compute64(As[db], Bs1, wm, wn, l, acc);
    db ^= 1;
  }

  const int q4 = (l >> 4) * 4, cl = l & 15;
  #pragma unroll
  for (int i = 0; i < 4; ++i)
    #pragma unroll
    for (int j = 0; j < 2; ++j) {
      const int col = bn + wn + 16 * j + cl;
      const float bs = bias[col];
      #pragma unroll
      for (int r = 0; r < 4; ++r) {
        const int row = bm + wm + 16 * i + q4 + r;
        float o = fmaxf(acc[i][j][r] + bs, 0.f);
        C[(size_t)row * 512 + col] = (unsigned short)f2bf(o);
      }
    }
}

// ---------------------------------------------------------------------------
// Grouped layer-2 GEMM, same 48 KB single-B template. A (bf16) gload-staged
// distance 1 issued after bar2 (full step in flight). K=512 (8 steps).
// v out bf16, q/a out fp32. grid = 496.
__global__ __launch_bounds__(512, 6) void l2_gemm(
    const unsigned short* __restrict__ vtb, const unsigned short* __restrict__ qtb,
    const unsigned short* __restrict__ atb,
    const unsigned short* __restrict__ Wvrb, const unsigned short* __restrict__ Wqrb,
    const unsigned short* __restrict__ Warb,
    const float* __restrict__ bvr, const float* __restrict__ bqr,
    const float* __restrict__ bar_,
    unsigned short* __restrict__ vrb, float* __restrict__ q_r, float* __restrict__ a_r)
{
  __shared__ __align__(16) unsigned short As[2][8192];
  __shared__ __align__(16) unsigned short Bs1[8192];
  const int bx = blockIdx.x;
  int grp, gx, gy;
  const unsigned short *A16, *W;
  const float* bias;
  if (bx < 400) {
    grp = 0; const int xcd = bx & 7, j = bx >> 3; const int m = xcd * 50 + j;
    gy = m >> 2; gx = m & 3; A16 = vtb; W = Wvrb; bias = bvr;
  } else if (bx < 456) {
    grp = 1; const int lo = bx - 400; gy = lo >> 2; gx = lo & 3;
    A16 = qtb; W = Wqrb; bias = bqr;
  } else {
    grp = 2; const int lo = bx - 456; gy = lo >> 2; gx = lo & 3;
    A16 = atb; W = Warb; bias = bar_;
  }
  const int nsteps = 8;
  const int bm = gy * 128, bn = gx * 128;
  const int t = threadIdx.x;
  const int w = t >> 6, l = t & 63;
  const int wm = (w >> 2) * 64, wn = (w & 3) * 32;
  const unsigned short* Wrow = W + (size_t)bn * 512;

  f32x4 acc[4][2];
  #pragma unroll
  for (int i = 0; i < 4; ++i)
    #pragma unroll
    for (int j = 0; j < 2; ++j) acc[i][j] = f32x4{0.f, 0.f, 0.f, 0.f};

  stage_swz8(A16 + (size_t)bm * 512, 512, As[0], t);   // A[0]

  int db = 0;
  for (int step = 0; step < nsteps; ++step) {
    __syncthreads();                                   // bar1
    stage_swz8(Wrow + step * 64, 512, Bs1, t);         // B[k]
    __syncthreads();                                   // bar2
    if (step + 1 < nsteps)
      stage_swz8(A16 + (size_t)bm * 512 + (step + 1) * 64, 512, As[db ^ 1], t);
    compute64(As[db], Bs1, wm, wn, l, acc);
    db ^= 1;
  }

  const int q4 = (l >> 4) * 4, cl = l & 15;
  #pragma unroll
  for (int i = 0; i < 4; ++i)
    #pragma unroll
    for (int j = 0; j < 2; ++j) {
      const int col = bn + wn + 16 * j + cl;
      const float bs = bias[col];
      #pragma unroll
      for (int r = 0; r < 4; ++r) {
        const int row = bm + wm + 16 * i + q4 + r;
        float o = fmaxf(acc[i][j][r] + bs, 0.f);
        if (grp == 0)      vrb[(size_t)row * 512 + col] = (unsigned short)f2bf(o);
        else if (grp == 1) q_r[(size_t)row * 512 + col] = o;
        else               a_r[(size_t)row * 512 + col] = o;
      }
    }
}

// ---------------------------------------------------------------------------
__global__ void tsum_kernel(const float* __restrict__ T, float* __restrict__ Tsum)
{
  const int idx = blockIdx.x * 256 + threadIdx.x;
  float s = 0.f;
  #pragma unroll
  for (int r = 0; r < RANK_; ++r) s += T[r * 8192 + idx];
  Tsum[idx] = s;
}

// ---------------------------------------------------------------------------
// Per (b,n): U = Tsum x q_ ; WmatT[b, col, n*16+i] = bf16(U x a_)
// WmatT padded to 320 rows (cols 280..319 unwritten).
__global__ __launch_bounds__(256) void build_w_kernel(
    const float* __restrict__ q_, const float* __restrict__ a_,
    const float* __restrict__ Tsum, unsigned short* __restrict__ WmatT)
{
  const int n = blockIdx.x, b = blockIdx.y, t = threadIdx.x;
  __shared__ float Ts[8192];
  __shared__ float U[14 * 544];

  #pragma unroll
  for (int s = 0; s < 8; ++s)
    ((float4*)Ts)[s * 256 + t] = ((const float4*)Tsum)[s * 256 + t];
  __syncthreads();

  {
    const int i = t >> 4, k = t & 15;
    float acc0[NQ_], acc1[NQ_];
    #pragma unroll
    for (int q = 0; q < NQ_; ++q) { acc0[q] = 0.f; acc1[q] = 0.f; }
    const float* qbase = q_ + (size_t)b * NQ_ * HDIM + n * 16;
    #pragma unroll
    for (int j = 0; j < 16; ++j) {
      float2 ts = *(const float2*)&Ts[i * 512 + j * 32 + k * 2];
      #pragma unroll
      for (int q = 0; q < NQ_; ++q) {
        float qv = qbase[q * HDIM + j];
        acc0[q] += ts.x * qv;
        acc1[q] += ts.y * qv;
      }
    }
    #pragma unroll
    for (int q = 0; q < NQ_; ++q) {
      float2 uu; uu.x = acc0[q]; uu.y = acc1[q];
      *(float2*)&U[q * 544 + i * 34 + k * 2] = uu;
    }
  }
  __syncthreads();

  if ((t >> 4) < NQ_) {
    const int q = t >> 4, i = t & 15;
    float acc0[NA_], acc1[NA_];
    #pragma unroll
    for (int a = 0; a < NA_; ++a) { acc0[a] = 0.f; acc1[a] = 0.f; }
    const float* abase = a_ + (size_t)b * NA_ * HDIM + n * 16;
    #pragma unroll
    for (int k = 0; k < 16; ++k) {
      float2 uu = *(const float2*)&U[q * 544 + i * 34 + k * 2];
      #pragma unroll
      for (int a = 0; a < NA_; ++a) {
        float av = abase[a * HDIM + k];
        acc0[a] += uu.x * av;
        acc1[a] += uu.y * av;
      }
    }
    unsigned short* wb = WmatT + (size_t)b * 320 * 512 + (n * 16 + i);
    #pragma unroll
    for (int a = 0; a < NA_; ++a) {
      wb[(size_t)((q * 10 + a) * 2 + 0) * 512] = (unsigned short)f2bf(acc0[a]);
      wb[(size_t)((q * 10 + a) * 2 + 1) * 512] = (unsigned short)f2bf(acc1[a]);
    }
  }
}

// ---------------------------------------------------------------------------
// Stage one BK=32 K-slice of final_mfma's A (64x32) and B (160x32) tiles.
__device__ __forceinline__ void final_stage(
    const unsigned short* __restrict__ Vrb, const unsigned short* __restrict__ Wb,
    int b, int mh, int n0, int k0, int t,
    unsigned short* Asb, unsigned short* Bsb)
{
  const int w = t >> 6, l = t & 63;
  {
    int grow = b * NV_ + mh * 64 + w * 16 + (l >> 2);
    if (grow > B_ * NV_ - 1) grow = B_ * NV_ - 1;   // clamp pad rows
    gload_lds16(Vrb + (size_t)grow * HDIM + k0 + (l & 3) * 8, &Asb[w * 512]);
  }
  #pragma unroll
  for (int c = 0; c < 3; ++c) {
    const int base = c * 256 + w * 64;   // 640 chunks of 16B
    if (base < 640) {
      const int li = base + l;
      const int nrow = li >> 2, ko2 = (li & 3) * 8;
      gload_lds16(Wb + (size_t)(n0 + nrow) * 512 + k0 + ko2, &Bsb[base * 8]);
    }
  }
}

// ---------------------------------------------------------------------------
// out[b,100,280] = v_[b,100,512] @ WmatT[b,320,512]^T
// grid (4, 128): blockIdx.x = mh*2 + nh; 64-row m-tile, 160-col n-tile.
// BK=32, 16 steps, 1-step-prefetch double buffer.
__global__ __launch_bounds__(256) void final_mfma(
    const unsigned short* __restrict__ Vrb, const unsigned short* __restrict__ WmatT,
    float* __restrict__ out)
{
  __shared__ __align__(16) unsigned short As[2][2048];   // [64][32]
  __shared__ __align__(16) unsigned short Bs[2][5120];   // [160][32]
  const int b  = blockIdx.y;
  const int mh = blockIdx.x >> 1;
  const int n0 = (blockIdx.x & 1) * 160;
  const int t = threadIdx.x;
  const int w = t >> 6, l = t & 63;
  const int wm = (w >> 1) * 32;   // 0,32 within 64-row tile
  const int wn = (w & 1) * 80;    // 0,80 within 160-col tile

  f32x4 acc[2][5];
  #pragma unroll
  for (int mi = 0; mi < 2; ++mi)
    #pragma unroll
    for (int nj = 0; nj < 5; ++nj) acc[mi][nj] = f32x4{0.f, 0.f, 0.f, 0.f};

  const unsigned short* Wb = WmatT + (size_t)b * 320 * 512;

  final_stage(Vrb, Wb, b, mh, n0, 0, t, As[0], Bs[0]);
  __syncthreads();

  for (int step = 0; step < 16; ++step) {
    const int db = step & 1;
    if (step + 1 < 16)
      final_stage(Vrb, Wb, b, mh, n0, (step + 1) * 32, t, As[db ^ 1], Bs[db ^ 1]);

    Frag fa[2], fb[5];
    #pragma unroll
    for (int mi = 0; mi < 2; ++mi)
      fa[mi].u = *(const uint4*)&As[db][(wm + mi * 16 + (l & 15)) * 32 + (l >> 4) * 8];
    #pragma unroll
    for (int nj = 0; nj < 5; ++nj)
      fb[nj].u = *(const uint4*)&Bs[db][(wn + nj * 16 + (l & 15)) * 32 + (l >> 4) * 8];
    #pragma unroll
    for (int mi = 0; mi < 2; ++mi)
      #pragma unroll
      for (int nj = 0; nj < 5; ++nj)
        acc[mi][nj] = __builtin_amdgcn_mfma_f32_16x16x32_bf16(fa[mi].v, fb[nj].v, acc[mi][nj], 0, 0, 0);
    __syncthreads();
  }

  #pragma unroll
  for (int mi = 0; mi < 2; ++mi)
    #pragma unroll
    for (int nj = 0; nj < 5; ++nj) {
      const int col = n0 + wn + nj * 16 + (l & 15);
      if (col < 280) {
        #pragma unroll
        for (int r = 0; r < 4; ++r) {
          const int row = mh * 64 + wm + mi * 16 + (l >> 4) * 4 + r;
          if (row < NV_)
            out[((size_t)b * NV_ + row) * 280 + col] = acc[mi][nj][r];
        }
      }
    }
}

// ---------------------------------------------------------------------------
extern "C" void kernel_launch(void* const* d_in, const int* in_sizes, int n_in,
                              void* d_out, int out_size, void* d_ws, size_t ws_size,
                              hipStream_t stream)
{
  const float* v   = (const float*)d_in[0];
  const float* q   = (const float*)d_in[1];
  const float* a   = (const float*)d_in[2];
  const float* Wv  = (const float*)d_in[3];
  const float* bv  = (const float*)d_in[4];
  const float* Wq  = (const float*)d_in[5];
  const float* bq  = (const float*)d_in[6];
  const float* Wa  = (const float*)d_in[7];
  const float* ba  = (const float*)d_in[8];
  const float* Wvr = (const float*)d_in[9];
  const float* bvr = (const float*)d_in[10];
  const float* Wqr = (const float*)d_in[11];
  const float* bqr = (const float*)d_in[12];
  const float* War = (const float*)d_in[13];
  const float* bar = (const float*)d_in[14];
  const float* T   = (const float*)d_in[15];

  unsigned short* wsu = (unsigned short*)d_ws;
  float* wsf = (float*)d_ws;

  // region A (ushort): WmatT [0 .. 20,971,520) — early overlay: bf16 q/a/weights
  unsigned short* WmatT = wsu;
  unsigned short* qb    = wsu;              //  1,835,008 (dead after l1)
  unsigned short* ab    = wsu + 1835008;    //  1,310,720 (dead after l1)
  unsigned short* Wvb   = wsu + 3145728;    //  1,048,576 (dead after l1)
  unsigned short* Wqb   = wsu + 4194304;    //    524,288
  unsigned short* Wab   = wsu + 4718592;    //    524,288
  unsigned short* Wvrb  = wsu + 5242880;    //    262,144 (dead after l2)
  unsigned short* Wqrb  = wsu + 5505024;    //    262,144
  unsigned short* Warb  = wsu + 5767168;    //    262,144  end 6,029,312 < 20.97M ok
  // persistent bf16 intermediates
  unsigned short* vtb   = wsu + 20971520;   //  6,553,600
  unsigned short* qtb   = wsu + 27525120;   //    917,504
  unsigned short* atb   = wsu + 28442624;   //    655,360
  unsigned short* vrb   = wsu + 29097984;   //  6,553,600  end 35,651,584 ush
  // fp32 region
  float* q_r  = wsf + 17825792;             //    917,504 f
  float* a_r  = wsf + 18743296;             //    655,360 f
  float* Tsum = wsf + 19398656;             //      8,192 f   (end 77.6 MB)

  cvt_kernel<<<2944, 256, 0, stream>>>(q, a, Wv, Wq, Wa, Wvr, Wqr, War, wsu);

  l1_gemm<<<496, 512, 0, stream>>>(v, qb, ab, Wvb, Wqb, Wab, bv, bq, ba,
                                   vtb, qtb, atb);
  l2_gemm<<<496, 512, 0, stream>>>(vtb, qtb, atb, Wvrb, Wqrb, Warb,
                                   bvr, bqr, bar, vrb, q_r, a_r);

  tsum_kernel<<<32, 256, 0, stream>>>(T, Tsum);
  build_w_kernel<<<dim3(32, 128), 256, 0, stream>>>(q_r, a_r, Tsum, WmatT);
  final_mfma<<<dim3(4, 128), 256, 0, stream>>>(vrb, WmatT, (float*)d_out);
}

// Round 7
// 325.267 us; speedup vs baseline: 3.4899x; 1.4262x over previous
//
#include <hip/hip_runtime.h>
#include <cstddef>
#include <cstdint>

#define B_    128
#define NV_   100
#define NQ_   14
#define NA_   10
#define HDIM  512
#define RANK_ 32
#define HD_   16
#define G_    2

typedef __bf16 bf16x8 __attribute__((ext_vector_type(8)));
typedef float  f32x4  __attribute__((ext_vector_type(4)));
union Frag { uint4 u; bf16x8 v; };

__device__ __forceinline__ unsigned int f2bf(float f) {
  unsigned int u = __float_as_uint(f);
  u = (u + 0x7FFFu + ((u >> 16) & 1u)) >> 16;
  return u & 0xFFFFu;
}

__device__ __forceinline__ void gload_lds16(const unsigned short* gp,
                                            unsigned short* dp) {
  __builtin_amdgcn_global_load_lds(
      (const __attribute__((address_space(1))) void*)gp,
      (__attribute__((address_space(3))) void*)dp, 16, 0, 0);
}

// ---------------------------------------------------------------------------
// fp32 -> bf16 for q, a, and the six weight matrices (NOT v — converted inline
// in l1_gemm). dst is contiguous in this exact order. Blocks >= 2944 compute
// Tsum = sum_r T[r] (fused former tsum_kernel; independent work, same launch).
__global__ __launch_bounds__(256) void cvt_kernel(
    const float* __restrict__ s0, const float* __restrict__ s1,
    const float* __restrict__ s2, const float* __restrict__ s3,
    const float* __restrict__ s4, const float* __restrict__ s5,
    const float* __restrict__ s6, const float* __restrict__ s7,
    unsigned short* __restrict__ dst,
    const float* __restrict__ T, float* __restrict__ Tsum)
{
  const int blk = blockIdx.x;
  if (blk >= 2944) {                       // tsum tail: 32 blocks
    const int idx = (blk - 2944) * 256 + threadIdx.x;
    float s = 0.f;
    #pragma unroll
    for (int r = 0; r < RANK_; ++r) s += T[r * 8192 + idx];
    Tsum[idx] = s;
    return;
  }
  const int pref[8] = {896, 1536, 2048, 2304, 2560, 2688, 2816, 2944};
  const float* srcs[8] = {s0, s1, s2, s3, s4, s5, s6, s7};
  int seg = 0;
  #pragma unroll
  for (int i = 0; i < 7; ++i) if (blk >= pref[i]) seg = i + 1;
  const int base_chunk = seg ? pref[seg - 1] : 0;
  const size_t loc = (size_t)(blk - base_chunk) * 2048 + threadIdx.x * 8;
  const float* s = srcs[seg] + loc;
  float4 f0 = *(const float4*)s;
  float4 f1 = *(const float4*)(s + 4);
  ushort4 o0, o1;
  o0.x = f2bf(f0.x); o0.y = f2bf(f0.y); o0.z = f2bf(f0.z); o0.w = f2bf(f0.w);
  o1.x = f2bf(f1.x); o1.y = f2bf(f1.y); o1.z = f2bf(f1.z); o1.w = f2bf(f1.w);
  unsigned short* d = dst + (size_t)blk * 2048 + threadIdx.x * 8;
  *(ushort4*)d = o0;
  *(ushort4*)(d + 4) = o1;
}

// ---------------------------------------------------------------------------
// Stage a 128x64 bf16 tile from global (row stride K elems) into LDS via
// global_load_lds (linear dest), 512 threads: 1024 16B-slots, 2 per thread.
// LDS layout: byte = row*128 + phys*16, phys = dataslot ^ (row&7)
// (XOR swizzle, conflict-free ds_read_b128 — verified SQ_LDS_BANK_CONFLICT=0).
// Swizzle applied on the per-lane GLOBAL source (m173 pattern).
__device__ __forceinline__ void stage_swz8(const unsigned short* __restrict__ src,
                                           int K, unsigned short* dst, int t)
{
  const int wb = t & 448;   // wave_id * 64 (wave-uniform)
  const int l = t & 63;
  #pragma unroll
  for (int i = 0; i < 2; ++i) {
    const int sb = i * 512 + wb;           // uniform 16B-slot base
    const int li = sb + l;                 // 0..1023
    const int row = li >> 3;
    const int p = li & 7;
    const int s = p ^ (row & 7);           // data slot held at phys slot p
    gload_lds16(src + (size_t)row * K + s * 8, dst + sb * 8);
  }
}

// Convert 16 fp32 (4 float4) to bf16 and write swizzled into a 128x64 A tile.
// Thread owns row ar, data slots {2*kq, 2*kq+1}.
__device__ __forceinline__ void cvt_write(const float4 f[4], unsigned short* Abuf,
                                          int ar, int kq)
{
  unsigned short* base = Abuf + ar * 64;
  #pragma unroll
  for (int j = 0; j < 2; ++j) {
    uint4 p;
    p.x = f2bf(f[2*j].x)   | (f2bf(f[2*j].y)   << 16);
    p.y = f2bf(f[2*j].z)   | (f2bf(f[2*j].w)   << 16);
    p.z = f2bf(f[2*j+1].x) | (f2bf(f[2*j+1].y) << 16);
    p.w = f2bf(f[2*j+1].z) | (f2bf(f[2*j+1].w) << 16);
    const int s = (kq * 2 + j) ^ (ar & 7);
    *(uint4*)&base[s * 8] = p;
  }
}

// ---------------------------------------------------------------------------
// Grouped layer-1 GEMM. 128x128 tiles, BK=64, 512 threads (8 waves, wave tile
// 64x32), double-buffered LDS. v-group: 2-deep register pipeline for the fp32
// A panel (load k+2 -> regs, convert k+1 -> LDS, compute k). EXACT Round-2
// structure (87.5 us proven; (512,4) = no spill). grid = 496.
__global__ __launch_bounds__(512, 4) void l1_gemm(
    const float* __restrict__ v,
    const unsigned short* __restrict__ qb, const unsigned short* __restrict__ ab,
    const unsigned short* __restrict__ Wvb, const unsigned short* __restrict__ Wqb,
    const unsigned short* __restrict__ Wab,
    const float* __restrict__ bv, const float* __restrict__ bq,
    const float* __restrict__ ba,
    unsigned short* __restrict__ vtb, unsigned short* __restrict__ qtb,
    unsigned short* __restrict__ atb)
{
  __shared__ __align__(16) unsigned short As[2][8192];   // [dbuf][128][64]
  __shared__ __align__(16) unsigned short Bs[2][8192];
  const int bx = blockIdx.x;
  int grp, gx, gy, K;
  const unsigned short *A16 = qb, *W;
  const float* bias;
  unsigned short* C;
  if (bx < 400) {
    grp = 0; const int xcd = bx & 7, j = bx >> 3; const int m = xcd * 50 + j;
    gy = m >> 2; gx = m & 3; W = Wvb; bias = bv; C = vtb; K = 2048;
  } else if (bx < 456) {
    grp = 1; const int lo = bx - 400; gy = lo >> 2; gx = lo & 3;
    A16 = qb; W = Wqb; bias = bq; C = qtb; K = 1024;
  } else {
    grp = 2; const int lo = bx - 456; gy = lo >> 2; gx = lo & 3;
    A16 = ab; W = Wab; bias = ba; C = atb; K = 1024;
  }
  const int nsteps = K >> 6;
  const int bm = gy * 128, bn = gx * 128;
  const int t = threadIdx.x;
  const int w = t >> 6, l = t & 63;
  const int wm = (w >> 2) * 64, wn = (w & 3) * 32;

  f32x4 acc[4][2];
  #pragma unroll
  for (int i = 0; i < 4; ++i)
    #pragma unroll
    for (int j = 0; j < 2; ++j) acc[i][j] = f32x4{0.f, 0.f, 0.f, 0.f};

  // v-group A staging: thread owns 16 floats (quarter row) per step
  const int ar = t >> 2, kq = t & 3;
  const float* vrow = (grp == 0)
      ? v + (size_t)(bm + ar) * 2048 + kq * 16 : (const float*)nullptr;
  float4 R0[4], R1[4];

  // ---- prologue
  stage_swz8(W + (size_t)bn * K, K, Bs[0], t);
  if (grp == 0) {
    #pragma unroll
    for (int i = 0; i < 4; ++i) R0[i] = ((const float4*)vrow)[i];
    #pragma unroll
    for (int i = 0; i < 4; ++i) R1[i] = ((const float4*)(vrow + 64))[i];
    cvt_write(R0, As[0], ar, kq);
  } else {
    stage_swz8(A16 + (size_t)bm * K, K, As[0], t);
  }
  __syncthreads();

  for (int step = 0; step < nsteps; ++step) {
    const int db = step & 1;
    const bool hn = (step + 1) < nsteps;
    if (hn) stage_swz8(W + (size_t)bn * K + (step + 1) * 64, K, Bs[db ^ 1], t);
    if (grp == 0) {
      if (step + 2 < nsteps) {
        const float* p = vrow + (step + 2) * 64;
        if (db == 0) {
          #pragma unroll
          for (int i = 0; i < 4; ++i) R0[i] = ((const float4*)p)[i];
        } else {
          #pragma unroll
          for (int i = 0; i < 4; ++i) R1[i] = ((const float4*)p)[i];
        }
      }
      if (hn) {
        if (db == 0) cvt_write(R1, As[1], ar, kq);
        else         cvt_write(R0, As[0], ar, kq);
      }
    } else if (hn) {
      stage_swz8(A16 + (size_t)bm * K + (step + 1) * 64, K, As[db ^ 1], t);
    }
    const unsigned short* Ad = As[db];
    const unsigned short* Bd = Bs[db];
    #pragma unroll
    for (int ks = 0; ks < 2; ++ks) {
      Frag fa[4], fb[2];
      #pragma unroll
      for (int i = 0; i < 4; ++i) {
        const int r = wm + 16 * i + (l & 15);
        fa[i].u = *(const uint4*)&Ad[r * 64 + (((ks * 4 + (l >> 4)) ^ (r & 7)) * 8)];
      }
      #pragma unroll
      for (int j = 0; j < 2; ++j) {
        const int r = wn + 16 * j + (l & 15);
        fb[j].u = *(const uint4*)&Bd[r * 64 + (((ks * 4 + (l >> 4)) ^ (r & 7)) * 8)];
      }
      #pragma unroll
      for (int i = 0; i < 4; ++i)
        #pragma unroll
        for (int j = 0; j < 2; ++j)
          acc[i][j] = __builtin_amdgcn_mfma_f32_16x16x32_bf16(fa[i].v, fb[j].v, acc[i][j], 0, 0, 0);
    }
    __syncthreads();
  }

  const int q4 = (l >> 4) * 4, cl = l & 15;
  #pragma unroll
  for (int i = 0; i < 4; ++i)
    #pragma unroll
    for (int j = 0; j < 2; ++j) {
      const int col = bn + wn + 16 * j + cl;
      const float bs = bias[col];
      #pragma unroll
      for (int r = 0; r < 4; ++r) {
        const int row = bm + wm + 16 * i + q4 + r;
        float o = fmaxf(acc[i][j][r] + bs, 0.f);
        C[(size_t)row * 512 + col] = (unsigned short)f2bf(o);
      }
    }
}

// ---------------------------------------------------------------------------
// Grouped layer-2 GEMM, EXACT Round-2 structure. K=512 (8 steps), all-bf16
// gload_lds staging. v out bf16, q/a out fp32. grid = 496.
__global__ __launch_bounds__(512, 4) void l2_gemm(
    const unsigned short* __restrict__ vtb, const unsigned short* __restrict__ qtb,
    const unsigned short* __restrict__ atb,
    const unsigned short* __restrict__ Wvrb, const unsigned short* __restrict__ Wqrb,
    const unsigned short* __restrict__ Warb,
    const float* __restrict__ bvr, const float* __restrict__ bqr,
    const float* __restrict__ bar_,
    unsigned short* __restrict__ vrb, float* __restrict__ q_r, float* __restrict__ a_r)
{
  __shared__ __align__(16) unsigned short As[2][8192];
  __shared__ __align__(16) unsigned short Bs[2][8192];
  const int bx = blockIdx.x;
  int grp, gx, gy;
  const unsigned short *A16, *W;
  const float* bias;
  if (bx < 400) {
    grp = 0; const int xcd = bx & 7, j = bx >> 3; const int m = xcd * 50 + j;
    gy = m >> 2; gx = m & 3; A16 = vtb; W = Wvrb; bias = bvr;
  } else if (bx < 456) {
    grp = 1; const int lo = bx - 400; gy = lo >> 2; gx = lo & 3;
    A16 = qtb; W = Wqrb; bias = bqr;
  } else {
    grp = 2; const int lo = bx - 456; gy = lo >> 2; gx = lo & 3;
    A16 = atb; W = Warb; bias = bar_;
  }
  const int bm = gy * 128, bn = gx * 128;
  const int t = threadIdx.x;
  const int w = t >> 6, l = t & 63;
  const int wm = (w >> 2) * 64, wn = (w & 3) * 32;

  f32x4 acc[4][2];
  #pragma unroll
  for (int i = 0; i < 4; ++i)
    #pragma unroll
    for (int j = 0; j < 2; ++j) acc[i][j] = f32x4{0.f, 0.f, 0.f, 0.f};

  stage_swz8(W + (size_t)bn * 512, 512, Bs[0], t);
  stage_swz8(A16 + (size_t)bm * 512, 512, As[0], t);
  __syncthreads();

  for (int step = 0; step < 8; ++step) {
    const int db = step & 1;
    const bool hn = (step + 1) < 8;
    const int k0n = (step + 1) << 6;
    if (hn) {
      stage_swz8(W + (size_t)bn * 512 + k0n, 512, Bs[db ^ 1], t);
      stage_swz8(A16 + (size_t)bm * 512 + k0n, 512, As[db ^ 1], t);
    }
    const unsigned short* Ad = As[db];
    const unsigned short* Bd = Bs[db];
    #pragma unroll
    for (int ks = 0; ks < 2; ++ks) {
      Frag fa[4], fb[2];
      #pragma unroll
      for (int i = 0; i < 4; ++i) {
        const int r = wm + 16 * i + (l & 15);
        fa[i].u = *(const uint4*)&Ad[r * 64 + (((ks * 4 + (l >> 4)) ^ (r & 7)) * 8)];
      }
      #pragma unroll
      for (int j = 0; j < 2; ++j) {
        const int r = wn + 16 * j + (l & 15);
        fb[j].u = *(const uint4*)&Bd[r * 64 + (((ks * 4 + (l >> 4)) ^ (r & 7)) * 8)];
      }
      #pragma unroll
      for (int i = 0; i < 4; ++i)
        #pragma unroll
        for (int j = 0; j < 2; ++j)
          acc[i][j] = __builtin_amdgcn_mfma_f32_16x16x32_bf16(fa[i].v, fb[j].v, acc[i][j], 0, 0, 0);
    }
    __syncthreads();
  }

  const int q4 = (l >> 4) * 4, cl = l & 15;
  #pragma unroll
  for (int i = 0; i < 4; ++i)
    #pragma unroll
    for (int j = 0; j < 2; ++j) {
      const int col = bn + wn + 16 * j + cl;
      const float bs = bias[col];
      #pragma unroll
      for (int r = 0; r < 4; ++r) {
        const int row = bm + wm + 16 * i + q4 + r;
        float o = fmaxf(acc[i][j][r] + bs, 0.f);
        if (grp == 0)      vrb[(size_t)row * 512 + col] = (unsigned short)f2bf(o);
        else if (grp == 1) q_r[(size_t)row * 512 + col] = o;
        else               a_r[(size_t)row * 512 + col] = o;
      }
    }
}

// ---------------------------------------------------------------------------
// Per (b,n): U = Tsum x q_ ; WmatT[b, col, n*16+i] = bf16(U x a_)
// WmatT padded to 320 rows (cols 280..319 unwritten).
__global__ __launch_bounds__(256) void build_w_kernel(
    const float* __restrict__ q_, const float* __restrict__ a_,
    const float* __restrict__ Tsum, unsigned short* __restrict__ WmatT)
{
  const int n = blockIdx.x, b = blockIdx.y, t = threadIdx.x;
  __shared__ float Ts[8192];
  __shared__ float U[14 * 544];

  #pragma unroll
  for (int s = 0; s < 8; ++s)
    ((float4*)Ts)[s * 256 + t] = ((const float4*)Tsum)[s * 256 + t];
  __syncthreads();

  {
    const int i = t >> 4, k = t & 15;
    float acc0[NQ_], acc1[NQ_];
    #pragma unroll
    for (int q = 0; q < NQ_; ++q) { acc0[q] = 0.f; acc1[q] = 0.f; }
    const float* qbase = q_ + (size_t)b * NQ_ * HDIM + n * 16;
    #pragma unroll
    for (int j = 0; j < 16; ++j) {
      float2 ts = *(const float2*)&Ts[i * 512 + j * 32 + k * 2];
      #pragma unroll
      for (int q = 0; q < NQ_; ++q) {
        float qv = qbase[q * HDIM + j];
        acc0[q] += ts.x * qv;
        acc1[q] += ts.y * qv;
      }
    }
    #pragma unroll
    for (int q = 0; q < NQ_; ++q) {
      float2 uu; uu.x = acc0[q]; uu.y = acc1[q];
      *(float2*)&U[q * 544 + i * 34 + k * 2] = uu;
    }
  }
  __syncthreads();

  if ((t >> 4) < NQ_) {
    const int q = t >> 4, i = t & 15;
    float acc0[NA_], acc1[NA_];
    #pragma unroll
    for (int a = 0; a < NA_; ++a) { acc0[a] = 0.f; acc1[a] = 0.f; }
    const float* abase = a_ + (size_t)b * NA_ * HDIM + n * 16;
    #pragma unroll
    for (int k = 0; k < 16; ++k) {
      float2 uu = *(const float2*)&U[q * 544 + i * 34 + k * 2];
      #pragma unroll
      for (int a = 0; a < NA_; ++a) {
        float av = abase[a * HDIM + k];
        acc0[a] += uu.x * av;
        acc1[a] += uu.y * av;
      }
    }
    unsigned short* wb = WmatT + (size_t)b * 320 * 512 + (n * 16 + i);
    #pragma unroll
    for (int a = 0; a < NA_; ++a) {
      wb[(size_t)((q * 10 + a) * 2 + 0) * 512] = (unsigned short)f2bf(acc0[a]);
      wb[(size_t)((q * 10 + a) * 2 + 1) * 512] = (unsigned short)f2bf(acc1[a]);
    }
  }
}

// ---------------------------------------------------------------------------
// out[b,100,280] = v_[b,100,512] @ WmatT[b,320,512]^T
// grid (4, 128): blockIdx.x = mh*2 + nh; 64-row m-tile, 160-col n-tile.
// BK=64 (8 steps), XOR-swizzled LDS (l1-proven layout: conflict-free
// ds_read_b128), 1-step-prefetch double buffer. 256 threads, 56 KB LDS.
__global__ __launch_bounds__(256, 2) void final_mfma(
    const unsigned short* __restrict__ Vrb, const unsigned short* __restrict__ WmatT,
    float* __restrict__ out)
{
  __shared__ __align__(16) unsigned short As[2][4096];    // [64][64] swizzled
  __shared__ __align__(16) unsigned short Bs[2][10240];   // [160][64] swizzled
  const int b  = blockIdx.y;
  const int mh = blockIdx.x >> 1;
  const int n0 = (blockIdx.x & 1) * 160;
  const int t = threadIdx.x;
  const int w = t >> 6, l = t & 63;
  const int wb = w * 64;          // wave-uniform slot base for staging
  const int wm = (w >> 1) * 32;   // 0,32 within 64-row tile
  const int wn = (w & 1) * 80;    // 0,80 within 160-col tile

  f32x4 acc[2][5];
  #pragma unroll
  for (int mi = 0; mi < 2; ++mi)
    #pragma unroll
    for (int nj = 0; nj < 5; ++nj) acc[mi][nj] = f32x4{0.f, 0.f, 0.f, 0.f};

  const unsigned short* Wb = WmatT + (size_t)b * 320 * 512;

  // Stage one BK=64 K-slice: A 64x64 (512 slots), B 160x64 (1280 slots).
  // Same swizzle as l1: slot li -> row=li>>3, phys=li&7, data s = phys^(row&7).
  #define FINAL_STAGE(k0, Asb, Bsb)                                          \
    {                                                                        \
      _Pragma("unroll")                                                      \
      for (int i = 0; i < 2; ++i) {                                          \
        const int sb = i * 256 + wb;                                         \
        const int li = sb + l;                                               \
        const int row = li >> 3, s = (li & 7) ^ (row & 7);                   \
        int grow = b * NV_ + mh * 64 + row;                                  \
        if (grow > B_ * NV_ - 1) grow = B_ * NV_ - 1;                        \
        gload_lds16(Vrb + (size_t)grow * 512 + (k0) + s * 8, (Asb) + sb * 8);\
      }                                                                      \
      _Pragma("unroll")                                                      \
      for (int i = 0; i < 5; ++i) {                                          \
        const int sb = i * 256 + wb;                                         \
        const int li = sb + l;                                               \
        const int row = li >> 3, s = (li & 7) ^ (row & 7);                   \
        gload_lds16(Wb + (size_t)(n0 + row) * 512 + (k0) + s * 8,            \
                    (Bsb) + sb * 8);                                         \
      }                                                                      \
    }

  FINAL_STAGE(0, As[0], Bs[0]);
  __syncthreads();

  for (int step = 0; step < 8; ++step) {
    const int db = step & 1;
    if (step + 1 < 8)
      FINAL_STAGE((step + 1) * 64, As[db ^ 1], Bs[db ^ 1]);

    const unsigned short* Ad = As[db];
    const unsigned short* Bd = Bs[db];
    #pragma unroll
    for (int ks = 0; ks < 2; ++ks) {
      Frag fa[2], fb[5];
      #pragma unroll
      for (int mi = 0; mi < 2; ++mi) {
        const int r = wm + mi * 16 + (l & 15);
        fa[mi].u = *(const uint4*)&Ad[r * 64 + (((ks * 4 + (l >> 4)) ^ (r & 7)) * 8)];
      }
      #pragma unroll
      for (int nj = 0; nj < 5; ++nj) {
        const int r = wn + nj * 16 + (l & 15);
        fb[nj].u = *(const uint4*)&Bd[r * 64 + (((ks * 4 + (l >> 4)) ^ (r & 7)) * 8)];
      }
      #pragma unroll
      for (int mi = 0; mi < 2; ++mi)
        #pragma unroll
        for (int nj = 0; nj < 5; ++nj)
          acc[mi][nj] = __builtin_amdgcn_mfma_f32_16x16x32_bf16(fa[mi].v, fb[nj].v, acc[mi][nj], 0, 0, 0);
    }
    __syncthreads();
  }
  #undef FINAL_STAGE

  #pragma unroll
  for (int mi = 0; mi < 2; ++mi)
    #pragma unroll
    for (int nj = 0; nj < 5; ++nj) {
      const int col = n0 + wn + nj * 16 + (l & 15);
      if (col < 280) {
        #pragma unroll
        for (int r = 0; r < 4; ++r) {
          const int row = mh * 64 + wm + mi * 16 + (l >> 4) * 4 + r;
          if (row < NV_)
            out[((size_t)b * NV_ + row) * 280 + col] = acc[mi][nj][r];
        }
      }
    }
}

// ---------------------------------------------------------------------------
extern "C" void kernel_launch(void* const* d_in, const int* in_sizes, int n_in,
                              void* d_out, int out_size, void* d_ws, size_t ws_size,
                              hipStream_t stream)
{
  const float* v   = (const float*)d_in[0];
  const float* q   = (const float*)d_in[1];
  const float* a   = (const float*)d_in[2];
  const float* Wv  = (const float*)d_in[3];
  const float* bv  = (const float*)d_in[4];
  const float* Wq  = (const float*)d_in[5];
  const float* bq  = (const float*)d_in[6];
  const float* Wa  = (const float*)d_in[7];
  const float* ba  = (const float*)d_in[8];
  const float* Wvr = (const float*)d_in[9];
  const float* bvr = (const float*)d_in[10];
  const float* Wqr = (const float*)d_in[11];
  const float* bqr = (const float*)d_in[12];
  const float* War = (const float*)d_in[13];
  const float* bar = (const float*)d_in[14];
  const float* T   = (const float*)d_in[15];

  unsigned short* wsu = (unsigned short*)d_ws;
  float* wsf = (float*)d_ws;

  // region A (ushort): WmatT [0 .. 20,971,520) — early overlay: bf16 q/a/weights
  unsigned short* WmatT = wsu;
  unsigned short* qb    = wsu;              //  1,835,008 (dead after l1)
  unsigned short* ab    = wsu + 1835008;    //  1,310,720 (dead after l1)
  unsigned short* Wvb   = wsu + 3145728;    //  1,048,576 (dead after l1)
  unsigned short* Wqb   = wsu + 4194304;    //    524,288
  unsigned short* Wab   = wsu + 4718592;    //    524,288
  unsigned short* Wvrb  = wsu + 5242880;    //    262,144 (dead after l2)
  unsigned short* Wqrb  = wsu + 5505024;    //    262,144
  unsigned short* Warb  = wsu + 5767168;    //    262,144  end 6,029,312 < 20.97M ok
  // persistent bf16 intermediates
  unsigned short* vtb   = wsu + 20971520;   //  6,553,600
  unsigned short* qtb   = wsu + 27525120;   //    917,504
  unsigned short* atb   = wsu + 28442624;   //    655,360
  unsigned short* vrb   = wsu + 29097984;   //  6,553,600  end 35,651,584 ush
  // fp32 region
  float* q_r  = wsf + 17825792;             //    917,504 f
  float* a_r  = wsf + 18743296;             //    655,360 f
  float* Tsum = wsf + 19398656;             //      8,192 f   (end 77.6 MB)

  cvt_kernel<<<2976, 256, 0, stream>>>(q, a, Wv, Wq, Wa, Wvr, Wqr, War, wsu,
                                       T, Tsum);

  l1_gemm<<<496, 512, 0, stream>>>(v, qb, ab, Wvb, Wqb, Wab, bv, bq, ba,
                                   vtb, qtb, atb);
  l2_gemm<<<496, 512, 0, stream>>>(vtb, qtb, atb, Wvrb, Wqrb, Warb,
                                   bvr, bqr, bar, vrb, q_r, a_r);

  build_w_kernel<<<dim3(32, 128), 256, 0, stream>>>(q_r, a_r, Tsum, WmatT);
  final_mfma<<<dim3(4, 128), 256, 0, stream>>>(vrb, WmatT, (float*)d_out);
}